// Round 2
// baseline (158.263 us; speedup 1.0000x reference)
//
#include <hip/hip_runtime.h>

// MergeLayer: out = sigmoid(relu([z[e0]; z[e1]] @ W1 + b1) @ W2 + b2)
// Factored: g = z @ Wcat (+b1 on gi half)  -- node-level GEMM via bf16 MFMA
//           out[k] = sigmoid(dot(relu(gi[e0]+gj[e1]), W2) + b2)  -- edge gather
//
// Round-2 change: edge phase is memory-SYSTEM-throughput bound (ILP and
// occupancy both neutral): random 256B gathers over a 25.6MB working set see
// ~16% per-XCD L2 hit rate and hammer the Infinity Cache with scattered 128B
// granules. Fix = LOCALITY: one-pass counting scatter bins edges into
// 8 i-chunks x 32 j-chunks (1.6MB + 0.4MB per bucket); edge kernel pins
// i-chunk->XCD (blockIdx&7 heuristic) and sweeps j-buckets in order, so both
// gather streams are L2-resident. Per-edge arithmetic unchanged.
//
// ws layout: gi | gj | Wt | counters(257 u32) | records(256*cap uint2) | ovfl

#define DD 128
#define NBI 8
#define NBJ 32
#define NBK (NBI * NBJ)
#define OVCAP 16384

typedef __attribute__((ext_vector_type(8))) short short8;
typedef __attribute__((ext_vector_type(4))) float floatx4;

static __device__ __forceinline__ unsigned short f2bf(float f) {
  unsigned int u = __builtin_bit_cast(unsigned int, f);
  u += 0x7fffu + ((u >> 16) & 1u);   // round-to-nearest-even
  return (unsigned short)(u >> 16);
}
static __device__ __forceinline__ float bflo(unsigned int u) {
  return __builtin_bit_cast(float, u << 16);
}
static __device__ __forceinline__ float bfhi(unsigned int u) {
  return __builtin_bit_cast(float, u & 0xffff0000u);
}

// ---------- prelude: Wt[c][k] = Wcat[k][c] as bf16; also zero bucket counters
__global__ __launch_bounds__(256) void wt_build(
    const float* __restrict__ W1, unsigned short* __restrict__ Wt,
    unsigned int* __restrict__ counters) {
  if (counters && blockIdx.x == 0 && threadIdx.x <= NBK)
    counters[threadIdx.x] = 0u;   // 256 bucket cursors + overflow count
  const int g = blockIdx.x * 256 + threadIdx.x;  // 8192 threads total
  const int c = g >> 5;                          // 0..255
  const int kq = (g & 31) * 4;                   // 0..124
  const float* src = (c < 128) ? (W1 + c) : (W1 + 128 * 128 + (c - 128));
  ushort4 o;
  o.x = f2bf(src[(size_t)(kq + 0) * 128]);
  o.y = f2bf(src[(size_t)(kq + 1) * 128]);
  o.z = f2bf(src[(size_t)(kq + 2) * 128]);
  o.w = f2bf(src[(size_t)(kq + 3) * 128]);
  *(ushort4*)&Wt[c * 128 + kq] = o;
}

// ---------- node GEMM via mfma_f32_16x16x32_bf16 (A=W, B=z) ------------------
__global__ __launch_bounds__(256) void node_mfma(
    const float* __restrict__ z, const unsigned short* __restrict__ Wt,
    const float* __restrict__ b1, unsigned short* __restrict__ gi,
    unsigned short* __restrict__ gj, int n_nodes) {
  __shared__ unsigned short zb[64 * 136];  // 17.4 KB; row stride 136
  const int tid = threadIdx.x;
  const int nb = blockIdx.x * 64;

#pragma unroll
  for (int i = 0; i < 8; ++i) {
    int q = tid + i * 256;            // 2048 float4 = 64 nodes x 32
    int nl = q >> 5;
    int node = nb + nl; if (node >= n_nodes) node = n_nodes - 1;
    float4 v = ((const float4*)z)[(size_t)node * 32 + (q & 31)];
    ushort4 o;
    o.x = f2bf(v.x); o.y = f2bf(v.y); o.z = f2bf(v.z); o.w = f2bf(v.w);
    *(ushort4*)&zb[nl * 136 + (q & 31) * 4] = o;
  }

  const int w = tid >> 6, lane = tid & 63;
  const int l15 = lane & 15, quad = lane >> 4;

  short8 a[4][4];
#pragma unroll
  for (int tt = 0; tt < 4; ++tt) {
    const unsigned short* wrow =
        Wt + (size_t)((w * 4 + tt) * 16 + l15) * 128 + quad * 8;
#pragma unroll
    for (int s = 0; s < 4; ++s) a[tt][s] = *(const short8*)(wrow + s * 32);
  }

  floatx4 acc[4][4];  // [tt][nt]
#pragma unroll
  for (int tt = 0; tt < 4; ++tt) {
    floatx4 bias = {0.f, 0.f, 0.f, 0.f};
    if (w < 2) {
      float4 b4 = *(const float4*)&b1[(w * 4 + tt) * 16 + quad * 4];
      bias[0] = b4.x; bias[1] = b4.y; bias[2] = b4.z; bias[3] = b4.w;
    }
#pragma unroll
    for (int nt = 0; nt < 4; ++nt) acc[tt][nt] = bias;
  }

  __syncthreads();

#pragma unroll
  for (int nt = 0; nt < 4; ++nt) {
    short8 bz[4];
#pragma unroll
    for (int s = 0; s < 4; ++s)
      bz[s] = *(const short8*)&zb[(nt * 16 + l15) * 136 + s * 32 + quad * 8];
#pragma unroll
    for (int tt = 0; tt < 4; ++tt)
#pragma unroll
      for (int s = 0; s < 4; ++s)
        acc[tt][nt] =
            __builtin_amdgcn_mfma_f32_16x16x32_bf16(a[tt][s], bz[s], acc[tt][nt], 0, 0, 0);
  }

  unsigned short* base = (w < 2) ? gi : gj;
  const int cbase = w * 64 - ((w < 2) ? 0 : 128);
#pragma unroll
  for (int nt = 0; nt < 4; ++nt) {
    const int node = nb + nt * 16 + l15;
    if (node < n_nodes) {
#pragma unroll
      for (int tt = 0; tt < 4; ++tt) {
        const int c = cbase + tt * 16 + quad * 4;
        ushort4 o;
        o.x = f2bf(acc[tt][nt][0]); o.y = f2bf(acc[tt][nt][1]);
        o.z = f2bf(acc[tt][nt][2]); o.w = f2bf(acc[tt][nt][3]);
        *(ushort4*)&base[(size_t)node * 128 + c] = o;
      }
    }
  }
}

// ---------- edge bucketing: counting scatter into 8x32 (i,j)-chunk buckets ---
// Records pack i|j<<16 (requires n_nodes <= 65535; gated host-side) + edge id.
__global__ __launch_bounds__(256) void edge_bucket(
    const int* __restrict__ e, int E, int ci, int cj, int cap,
    unsigned int* __restrict__ counters,   // [0..255]=cursors, [256]=ovfl cnt
    uint2* __restrict__ recs, uint2* __restrict__ ovrecs) {
  __shared__ unsigned int hist[NBK];
  __shared__ unsigned int wbase[NBK];
  const int tid = threadIdx.x;
  const int nchunk = (E + gridDim.x - 1) / gridDim.x;
  const int e0 = blockIdx.x * nchunk;
  const int e1 = (e0 + nchunk < E) ? (e0 + nchunk) : E;
  hist[tid] = 0u;
  __syncthreads();
  for (int t = e0 + tid; t < e1; t += 256) {
    const int i = e[t], j = e[E + t];
    const int key = (i / ci) * NBJ + (j / cj);
    atomicAdd(&hist[key], 1u);
  }
  __syncthreads();
  const unsigned int h = hist[tid];
  wbase[tid] = h ? atomicAdd(&counters[tid], h) : 0u;
  __syncthreads();
  hist[tid] = 0u;   // reuse as intra-block cursor
  __syncthreads();
  for (int t = e0 + tid; t < e1; t += 256) {
    const int i = e[t], j = e[E + t];
    const int key = (i / ci) * NBJ + (j / cj);
    const unsigned int off = wbase[key] + atomicAdd(&hist[key], 1u);
    uint2 r;
    r.x = (unsigned int)i | ((unsigned int)j << 16);
    r.y = (unsigned int)t;
    if (off < (unsigned int)cap) {
      recs[(size_t)key * cap + off] = r;
    } else {
      const unsigned int op = atomicAdd(&counters[NBK], 1u);
      if (op < OVCAP) ovrecs[op] = r;   // statistically never; safety net
    }
  }
}

// ---------- edge phase: bucketed, XCD-pinned, 8 lanes per edge ---------------
static __device__ __forceinline__ float dot8(uint4 a, uint4 b, float4 w0, float4 w1) {
  float s;
  s = fmaxf(bflo(a.x) + bflo(b.x), 0.f) * w0.x;
  s = fmaf(fmaxf(bfhi(a.x) + bfhi(b.x), 0.f), w0.y, s);
  s = fmaf(fmaxf(bflo(a.y) + bflo(b.y), 0.f), w0.z, s);
  s = fmaf(fmaxf(bfhi(a.y) + bfhi(b.y), 0.f), w0.w, s);
  s = fmaf(fmaxf(bflo(a.z) + bflo(b.z), 0.f), w1.x, s);
  s = fmaf(fmaxf(bfhi(a.z) + bfhi(b.z), 0.f), w1.y, s);
  s = fmaf(fmaxf(bflo(a.w) + bflo(b.w), 0.f), w1.z, s);
  s = fmaf(fmaxf(bfhi(a.w) + bfhi(b.w), 0.f), w1.w, s);
  return s;
}

__global__ __launch_bounds__(256) void edge_mlp_b(
    const unsigned short* __restrict__ gi, const unsigned short* __restrict__ gj,
    const float* __restrict__ W2, const float* __restrict__ b2,
    float* __restrict__ out,
    const unsigned int* __restrict__ counters,
    const uint2* __restrict__ recs, const uint2* __restrict__ ovrecs, int cap) {
  const int p = threadIdx.x & 7;
  const float4* wv = (const float4*)W2;
  const float4 w0 = wv[p * 2],      w1 = wv[p * 2 + 1];
  const float4 w2 = wv[16 + p * 2], w3 = wv[16 + p * 2 + 1];
  const float bias2 = b2[0];

  // blockIdx&7 -> XCD (round-robin dispatch heuristic; perf-only, not corr.)
  const int xcd = blockIdx.x & 7;               // = i-bucket
  const int bslot = blockIdx.x >> 3;            // 0..255 within XCD
  const int g = bslot * 32 + (threadIdx.x >> 3);  // group 0..8191 per XCD

  for (int jb = 0; jb < NBJ; ++jb) {
    const int key = xcd * NBJ + jb;
    int cnt = (int)counters[key]; if (cnt > cap) cnt = cap;
    const uint2* br = recs + (size_t)key * cap;
    for (int t = g; t < cnt; t += 8192) {
      const uint2 r = br[t];                    // 8 lanes same addr: broadcast
      const int i = (int)(r.x & 0xffffu);
      const int j = (int)(r.x >> 16);
      const uint4* pi = (const uint4*)(gi + (size_t)i * 128);
      const uint4* pj = (const uint4*)(gj + (size_t)j * 128);
      uint4 a0 = pi[p], a1 = pi[8 + p];
      uint4 c0 = pj[p], c1 = pj[8 + p];
      float acc = dot8(a0, c0, w0, w1) + dot8(a1, c1, w2, w3);
      acc += __shfl_xor(acc, 1);
      acc += __shfl_xor(acc, 2);
      acc += __shfl_xor(acc, 4);
      if (p == 0) out[r.y] = 1.f / (1.f + __expf(-(acc + bias2)));
    }
  }

  // overflow safety net (normally empty)
  int ov = (int)counters[NBK]; if (ov > OVCAP) ov = OVCAP;
  for (int t = blockIdx.x * 32 + (threadIdx.x >> 3); t < ov; t += gridDim.x * 32) {
    const uint2 r = ovrecs[t];
    const int i = (int)(r.x & 0xffffu);
    const int j = (int)(r.x >> 16);
    const uint4* pi = (const uint4*)(gi + (size_t)i * 128);
    const uint4* pj = (const uint4*)(gj + (size_t)j * 128);
    uint4 a0 = pi[p], a1 = pi[8 + p];
    uint4 c0 = pj[p], c1 = pj[8 + p];
    float acc = dot8(a0, c0, w0, w1) + dot8(a1, c1, w2, w3);
    acc += __shfl_xor(acc, 1);
    acc += __shfl_xor(acc, 2);
    acc += __shfl_xor(acc, 4);
    if (p == 0) out[r.y] = 1.f / (1.f + __expf(-(acc + bias2)));
  }
}

// ---------- flat edge kernel (fallback: n_nodes > 65535 or mid-size ws) ------
__global__ __launch_bounds__(256) void edge_mlp(
    const int* __restrict__ e, const unsigned short* __restrict__ gi,
    const unsigned short* __restrict__ gj, const float* __restrict__ W2,
    const float* __restrict__ b2, float* __restrict__ out, int E) {
  const int p = threadIdx.x & 7;
  const float4* wv = (const float4*)W2;
  const float4 w0 = wv[p * 2],      w1 = wv[p * 2 + 1];
  const float4 w2 = wv[16 + p * 2], w3 = wv[16 + p * 2 + 1];
  const float bias2 = b2[0];
  const int stride = gridDim.x * 32;
  for (int edge = blockIdx.x * 32 + (threadIdx.x >> 3); edge < E; edge += stride) {
    const int i = e[edge];
    const int j = e[E + edge];
    const uint4* pi = (const uint4*)(gi + (size_t)i * 128);
    const uint4* pj = (const uint4*)(gj + (size_t)j * 128);
    uint4 a0 = pi[p], a1 = pi[8 + p];
    uint4 c0 = pj[p], c1 = pj[8 + p];
    float acc = dot8(a0, c0, w0, w1) + dot8(a1, c1, w2, w3);
    acc += __shfl_xor(acc, 1);
    acc += __shfl_xor(acc, 2);
    acc += __shfl_xor(acc, 4);
    if (p == 0) out[edge] = 1.f / (1.f + __expf(-(acc + bias2)));
  }
}

// ---------- fallback (workspace too small): wave per edge ---------------------
__global__ __launch_bounds__(256) void edge_direct(
    const int* __restrict__ e, const float* __restrict__ z,
    const float* __restrict__ W1, const float* __restrict__ b1,
    const float* __restrict__ W2, const float* __restrict__ b2,
    float* __restrict__ out, int E) {
  const int lane = threadIdx.x & 63;
  const int edge = (int)((blockIdx.x * 256u + threadIdx.x) >> 6);
  if (edge >= E) return;
  const int i = e[edge], j = e[E + edge];
  const float* zi = z + (size_t)i * 128;
  const float* zj = z + (size_t)j * 128;
  const int c0 = lane * 2;
  float h0 = b1[c0], h1 = b1[c0 + 1];
  for (int k = 0; k < 128; ++k) {
    float a = zi[k], b = zj[k];
    float2 wt = *(const float2*)&W1[(size_t)k * 128 + c0];
    float2 wb = *(const float2*)&W1[(size_t)(128 + k) * 128 + c0];
    h0 = fmaf(a, wt.x, h0); h1 = fmaf(a, wt.y, h1);
    h0 = fmaf(b, wb.x, h0); h1 = fmaf(b, wb.y, h1);
  }
  float s = fmaxf(h0, 0.f) * W2[c0] + fmaxf(h1, 0.f) * W2[c0 + 1];
#pragma unroll
  for (int off = 1; off < 64; off <<= 1) s += __shfl_xor(s, off);
  if (lane == 0) out[edge] = 1.f / (1.f + __expf(-(s + b2[0])));
}

extern "C" void kernel_launch(void* const* d_in, const int* in_sizes, int n_in,
                              void* d_out, int out_size, void* d_ws, size_t ws_size,
                              hipStream_t stream) {
  const float* z  = (const float*)d_in[0];
  const int*   e  = (const int*)d_in[1];
  const float* W1 = (const float*)d_in[2];
  const float* b1 = (const float*)d_in[3];
  const float* W2 = (const float*)d_in[4];
  const float* b2 = (const float*)d_in[5];
  float* out = (float*)d_out;
  const int n_nodes = in_sizes[0] / DD;  // 50000
  const int E = in_sizes[1] / 2;         // 600000

  const size_t g_bytes = (size_t)n_nodes * DD * sizeof(unsigned short);
  const size_t wt_bytes = 256 * 128 * sizeof(unsigned short);  // 64 KB
  const int cap = E / NBK * 2 + 2048;
  const size_t cnt_bytes = 2048;  // 257 u32, padded
  const size_t rec_bytes = (size_t)NBK * cap * sizeof(uint2);
  const size_t ov_bytes = (size_t)OVCAP * sizeof(uint2);
  const size_t need_bucketed =
      2 * g_bytes + wt_bytes + cnt_bytes + rec_bytes + ov_bytes;

  if (ws_size >= need_bucketed && n_nodes <= 65535 && n_nodes > 0) {
    unsigned short* gi = (unsigned short*)d_ws;
    unsigned short* gj = (unsigned short*)((char*)d_ws + g_bytes);
    unsigned short* Wt = (unsigned short*)((char*)d_ws + 2 * g_bytes);
    unsigned int* counters =
        (unsigned int*)((char*)d_ws + 2 * g_bytes + wt_bytes);
    uint2* recs = (uint2*)((char*)d_ws + 2 * g_bytes + wt_bytes + cnt_bytes);
    uint2* ovrecs = (uint2*)((char*)recs + rec_bytes);
    const int ci = (n_nodes + NBI - 1) / NBI;
    const int cj = (n_nodes + NBJ - 1) / NBJ;
    wt_build<<<32, 256, 0, stream>>>(W1, Wt, counters);
    edge_bucket<<<256, 256, 0, stream>>>(e, E, ci, cj, cap, counters, recs, ovrecs);
    node_mfma<<<(n_nodes + 63) / 64, 256, 0, stream>>>(z, Wt, b1, gi, gj, n_nodes);
    edge_mlp_b<<<2048, 256, 0, stream>>>(gi, gj, W2, b2, out, counters, recs,
                                         ovrecs, cap);
  } else if (ws_size >= 2 * g_bytes + wt_bytes) {
    unsigned short* gi = (unsigned short*)d_ws;
    unsigned short* gj = (unsigned short*)((char*)d_ws + g_bytes);
    unsigned short* Wt = (unsigned short*)((char*)d_ws + 2 * g_bytes);
    wt_build<<<32, 256, 0, stream>>>(W1, Wt, nullptr);
    node_mfma<<<(n_nodes + 63) / 64, 256, 0, stream>>>(z, Wt, b1, gi, gj, n_nodes);
    edge_mlp<<<2048, 256, 0, stream>>>(e, gi, gj, W2, b2, out, E);
  } else {
    edge_direct<<<(E + 3) / 4, 256, 0, stream>>>(e, z, W1, b1, W2, b2, out, E);
  }
}

// Round 3
// 142.952 us; speedup vs baseline: 1.1071x; 1.1071x over previous
//
#include <hip/hip_runtime.h>

// MergeLayer: out = sigmoid(relu([z[e0]; z[e1]] @ W1 + b1) @ W2 + b2)
// Factored: g = z @ Wcat (+b1 on gi half)  -- node-level GEMM via bf16 MFMA
//           out[k] = sigmoid(dot(relu(gi[e0]+gj[e1]), W2) + b2)  -- edge gather
//
// Round-3: round-2's 8x32 bucketing starved the machine -- per-(XCD,jb) phase
// had 2344 edges vs 8192 groups, so 71% of blocks exited instantly (measured
// Occupancy 25%, VALUBusy 28%, active waves ~saturated). Locality worked;
// parallelism didn't. Fix: NBJ=8 (9375 edges/phase > 8192 groups -> all
// blocks busy every phase; per-XCD L2 working set 1.6+1.6=3.2MB < 4MB) and
// prefetch the 8 bucket counts into registers (kills per-phase dependent
// counter load). Per-edge arithmetic unchanged.
//
// ws layout: gi | gj | Wt | counters(65 u32 pad) | records(64*cap uint2) | ovfl

#define DD 128
#define NBI 8
#define NBJ 8
#define NBK (NBI * NBJ)
#define OVCAP 16384

typedef __attribute__((ext_vector_type(8))) short short8;
typedef __attribute__((ext_vector_type(4))) float floatx4;

static __device__ __forceinline__ unsigned short f2bf(float f) {
  unsigned int u = __builtin_bit_cast(unsigned int, f);
  u += 0x7fffu + ((u >> 16) & 1u);   // round-to-nearest-even
  return (unsigned short)(u >> 16);
}
static __device__ __forceinline__ float bflo(unsigned int u) {
  return __builtin_bit_cast(float, u << 16);
}
static __device__ __forceinline__ float bfhi(unsigned int u) {
  return __builtin_bit_cast(float, u & 0xffff0000u);
}

// ---------- prelude: Wt[c][k] = Wcat[k][c] as bf16; also zero bucket counters
__global__ __launch_bounds__(256) void wt_build(
    const float* __restrict__ W1, unsigned short* __restrict__ Wt,
    unsigned int* __restrict__ counters) {
  if (counters && blockIdx.x == 0 && threadIdx.x <= NBK)
    counters[threadIdx.x] = 0u;   // 64 bucket cursors + overflow count
  const int g = blockIdx.x * 256 + threadIdx.x;  // 8192 threads total
  const int c = g >> 5;                          // 0..255
  const int kq = (g & 31) * 4;                   // 0..124
  const float* src = (c < 128) ? (W1 + c) : (W1 + 128 * 128 + (c - 128));
  ushort4 o;
  o.x = f2bf(src[(size_t)(kq + 0) * 128]);
  o.y = f2bf(src[(size_t)(kq + 1) * 128]);
  o.z = f2bf(src[(size_t)(kq + 2) * 128]);
  o.w = f2bf(src[(size_t)(kq + 3) * 128]);
  *(ushort4*)&Wt[c * 128 + kq] = o;
}

// ---------- node GEMM via mfma_f32_16x16x32_bf16 (A=W, B=z) ------------------
__global__ __launch_bounds__(256) void node_mfma(
    const float* __restrict__ z, const unsigned short* __restrict__ Wt,
    const float* __restrict__ b1, unsigned short* __restrict__ gi,
    unsigned short* __restrict__ gj, int n_nodes) {
  __shared__ unsigned short zb[64 * 136];  // 17.4 KB; row stride 136
  const int tid = threadIdx.x;
  const int nb = blockIdx.x * 64;

#pragma unroll
  for (int i = 0; i < 8; ++i) {
    int q = tid + i * 256;            // 2048 float4 = 64 nodes x 32
    int nl = q >> 5;
    int node = nb + nl; if (node >= n_nodes) node = n_nodes - 1;
    float4 v = ((const float4*)z)[(size_t)node * 32 + (q & 31)];
    ushort4 o;
    o.x = f2bf(v.x); o.y = f2bf(v.y); o.z = f2bf(v.z); o.w = f2bf(v.w);
    *(ushort4*)&zb[nl * 136 + (q & 31) * 4] = o;
  }

  const int w = tid >> 6, lane = tid & 63;
  const int l15 = lane & 15, quad = lane >> 4;

  short8 a[4][4];
#pragma unroll
  for (int tt = 0; tt < 4; ++tt) {
    const unsigned short* wrow =
        Wt + (size_t)((w * 4 + tt) * 16 + l15) * 128 + quad * 8;
#pragma unroll
    for (int s = 0; s < 4; ++s) a[tt][s] = *(const short8*)(wrow + s * 32);
  }

  floatx4 acc[4][4];  // [tt][nt]
#pragma unroll
  for (int tt = 0; tt < 4; ++tt) {
    floatx4 bias = {0.f, 0.f, 0.f, 0.f};
    if (w < 2) {
      float4 b4 = *(const float4*)&b1[(w * 4 + tt) * 16 + quad * 4];
      bias[0] = b4.x; bias[1] = b4.y; bias[2] = b4.z; bias[3] = b4.w;
    }
#pragma unroll
    for (int nt = 0; nt < 4; ++nt) acc[tt][nt] = bias;
  }

  __syncthreads();

#pragma unroll
  for (int nt = 0; nt < 4; ++nt) {
    short8 bz[4];
#pragma unroll
    for (int s = 0; s < 4; ++s)
      bz[s] = *(const short8*)&zb[(nt * 16 + l15) * 136 + s * 32 + quad * 8];
#pragma unroll
    for (int tt = 0; tt < 4; ++tt)
#pragma unroll
      for (int s = 0; s < 4; ++s)
        acc[tt][nt] =
            __builtin_amdgcn_mfma_f32_16x16x32_bf16(a[tt][s], bz[s], acc[tt][nt], 0, 0, 0);
  }

  unsigned short* base = (w < 2) ? gi : gj;
  const int cbase = w * 64 - ((w < 2) ? 0 : 128);
#pragma unroll
  for (int nt = 0; nt < 4; ++nt) {
    const int node = nb + nt * 16 + l15;
    if (node < n_nodes) {
#pragma unroll
      for (int tt = 0; tt < 4; ++tt) {
        const int c = cbase + tt * 16 + quad * 4;
        ushort4 o;
        o.x = f2bf(acc[tt][nt][0]); o.y = f2bf(acc[tt][nt][1]);
        o.z = f2bf(acc[tt][nt][2]); o.w = f2bf(acc[tt][nt][3]);
        *(ushort4*)&base[(size_t)node * 128 + c] = o;
      }
    }
  }
}

// ---------- edge bucketing: counting scatter into 8x8 (i,j)-chunk buckets ----
// Records pack i|j<<16 (requires n_nodes <= 65535; gated host-side) + edge id.
__global__ __launch_bounds__(256) void edge_bucket(
    const int* __restrict__ e, int E, int ci, int cj, int cap,
    unsigned int* __restrict__ counters,   // [0..63]=cursors, [64]=ovfl cnt
    uint2* __restrict__ recs, uint2* __restrict__ ovrecs) {
  __shared__ unsigned int hist[NBK];
  __shared__ unsigned int wbase[NBK];
  const int tid = threadIdx.x;
  const int nchunk = (E + gridDim.x - 1) / gridDim.x;
  const int e0 = blockIdx.x * nchunk;
  const int e1 = (e0 + nchunk < E) ? (e0 + nchunk) : E;
  if (tid < NBK) hist[tid] = 0u;
  __syncthreads();
  for (int t = e0 + tid; t < e1; t += 256) {
    const int i = e[t], j = e[E + t];
    const int key = (i / ci) * NBJ + (j / cj);
    atomicAdd(&hist[key], 1u);
  }
  __syncthreads();
  if (tid < NBK) {
    const unsigned int h = hist[tid];
    wbase[tid] = h ? atomicAdd(&counters[tid], h) : 0u;
  }
  __syncthreads();
  if (tid < NBK) hist[tid] = 0u;   // reuse as intra-block cursor
  __syncthreads();
  for (int t = e0 + tid; t < e1; t += 256) {
    const int i = e[t], j = e[E + t];
    const int key = (i / ci) * NBJ + (j / cj);
    const unsigned int off = wbase[key] + atomicAdd(&hist[key], 1u);
    uint2 r;
    r.x = (unsigned int)i | ((unsigned int)j << 16);
    r.y = (unsigned int)t;
    if (off < (unsigned int)cap) {
      recs[(size_t)key * cap + off] = r;
    } else {
      const unsigned int op = atomicAdd(&counters[NBK], 1u);
      if (op < OVCAP) ovrecs[op] = r;   // statistically never; safety net
    }
  }
}

// ---------- edge phase: bucketed, XCD-pinned, 8 lanes per edge ---------------
static __device__ __forceinline__ float dot8(uint4 a, uint4 b, float4 w0, float4 w1) {
  float s;
  s = fmaxf(bflo(a.x) + bflo(b.x), 0.f) * w0.x;
  s = fmaf(fmaxf(bfhi(a.x) + bfhi(b.x), 0.f), w0.y, s);
  s = fmaf(fmaxf(bflo(a.y) + bflo(b.y), 0.f), w0.z, s);
  s = fmaf(fmaxf(bfhi(a.y) + bfhi(b.y), 0.f), w0.w, s);
  s = fmaf(fmaxf(bflo(a.z) + bflo(b.z), 0.f), w1.x, s);
  s = fmaf(fmaxf(bfhi(a.z) + bfhi(b.z), 0.f), w1.y, s);
  s = fmaf(fmaxf(bflo(a.w) + bflo(b.w), 0.f), w1.z, s);
  s = fmaf(fmaxf(bfhi(a.w) + bfhi(b.w), 0.f), w1.w, s);
  return s;
}

__global__ __launch_bounds__(256) void edge_mlp_b(
    const unsigned short* __restrict__ gi, const unsigned short* __restrict__ gj,
    const float* __restrict__ W2, const float* __restrict__ b2,
    float* __restrict__ out,
    const unsigned int* __restrict__ counters,
    const uint2* __restrict__ recs, const uint2* __restrict__ ovrecs, int cap) {
  const int p = threadIdx.x & 7;
  const float4* wv = (const float4*)W2;
  const float4 w0 = wv[p * 2],      w1 = wv[p * 2 + 1];
  const float4 w2 = wv[16 + p * 2], w3 = wv[16 + p * 2 + 1];
  const float bias2 = b2[0];

  // blockIdx&7 -> XCD (round-robin dispatch heuristic; perf-only, not corr.)
  const int xcd = blockIdx.x & 7;               // = i-bucket
  const int bslot = blockIdx.x >> 3;            // 0..255 within XCD class
  const int g = bslot * 32 + (threadIdx.x >> 3);  // group 0..8191 per XCD

  // prefetch this XCD's 8 bucket counts into registers (no per-phase load)
  int cnts[NBJ];
#pragma unroll
  for (int jb = 0; jb < NBJ; ++jb) {
    int c = (int)counters[xcd * NBJ + jb];
    cnts[jb] = (c > cap) ? cap : c;
  }

#pragma unroll
  for (int jb = 0; jb < NBJ; ++jb) {
    const uint2* br = recs + (size_t)(xcd * NBJ + jb) * cap;
    for (int t = g; t < cnts[jb]; t += 8192) {
      const uint2 r = br[t];                    // 8 lanes same addr: broadcast
      const int i = (int)(r.x & 0xffffu);
      const int j = (int)(r.x >> 16);
      const uint4* pi = (const uint4*)(gi + (size_t)i * 128);
      const uint4* pj = (const uint4*)(gj + (size_t)j * 128);
      uint4 a0 = pi[p], a1 = pi[8 + p];
      uint4 c0 = pj[p], c1 = pj[8 + p];
      float acc = dot8(a0, c0, w0, w1) + dot8(a1, c1, w2, w3);
      acc += __shfl_xor(acc, 1);
      acc += __shfl_xor(acc, 2);
      acc += __shfl_xor(acc, 4);
      if (p == 0) out[r.y] = 1.f / (1.f + __expf(-(acc + bias2)));
    }
  }

  // overflow safety net (normally empty)
  int ov = (int)counters[NBK]; if (ov > OVCAP) ov = OVCAP;
  for (int t = blockIdx.x * 32 + (threadIdx.x >> 3); t < ov; t += gridDim.x * 32) {
    const uint2 r = ovrecs[t];
    const int i = (int)(r.x & 0xffffu);
    const int j = (int)(r.x >> 16);
    const uint4* pi = (const uint4*)(gi + (size_t)i * 128);
    const uint4* pj = (const uint4*)(gj + (size_t)j * 128);
    uint4 a0 = pi[p], a1 = pi[8 + p];
    uint4 c0 = pj[p], c1 = pj[8 + p];
    float acc = dot8(a0, c0, w0, w1) + dot8(a1, c1, w2, w3);
    acc += __shfl_xor(acc, 1);
    acc += __shfl_xor(acc, 2);
    acc += __shfl_xor(acc, 4);
    if (p == 0) out[r.y] = 1.f / (1.f + __expf(-(acc + bias2)));
  }
}

// ---------- flat edge kernel (fallback: n_nodes > 65535 or mid-size ws) ------
__global__ __launch_bounds__(256) void edge_mlp(
    const int* __restrict__ e, const unsigned short* __restrict__ gi,
    const unsigned short* __restrict__ gj, const float* __restrict__ W2,
    const float* __restrict__ b2, float* __restrict__ out, int E) {
  const int p = threadIdx.x & 7;
  const float4* wv = (const float4*)W2;
  const float4 w0 = wv[p * 2],      w1 = wv[p * 2 + 1];
  const float4 w2 = wv[16 + p * 2], w3 = wv[16 + p * 2 + 1];
  const float bias2 = b2[0];
  const int stride = gridDim.x * 32;
  for (int edge = blockIdx.x * 32 + (threadIdx.x >> 3); edge < E; edge += stride) {
    const int i = e[edge];
    const int j = e[E + edge];
    const uint4* pi = (const uint4*)(gi + (size_t)i * 128);
    const uint4* pj = (const uint4*)(gj + (size_t)j * 128);
    uint4 a0 = pi[p], a1 = pi[8 + p];
    uint4 c0 = pj[p], c1 = pj[8 + p];
    float acc = dot8(a0, c0, w0, w1) + dot8(a1, c1, w2, w3);
    acc += __shfl_xor(acc, 1);
    acc += __shfl_xor(acc, 2);
    acc += __shfl_xor(acc, 4);
    if (p == 0) out[edge] = 1.f / (1.f + __expf(-(acc + bias2)));
  }
}

// ---------- fallback (workspace too small): wave per edge ---------------------
__global__ __launch_bounds__(256) void edge_direct(
    const int* __restrict__ e, const float* __restrict__ z,
    const float* __restrict__ W1, const float* __restrict__ b1,
    const float* __restrict__ W2, const float* __restrict__ b2,
    float* __restrict__ out, int E) {
  const int lane = threadIdx.x & 63;
  const int edge = (int)((blockIdx.x * 256u + threadIdx.x) >> 6);
  if (edge >= E) return;
  const int i = e[edge], j = e[E + edge];
  const float* zi = z + (size_t)i * 128;
  const float* zj = z + (size_t)j * 128;
  const int c0 = lane * 2;
  float h0 = b1[c0], h1 = b1[c0 + 1];
  for (int k = 0; k < 128; ++k) {
    float a = zi[k], b = zj[k];
    float2 wt = *(const float2*)&W1[(size_t)k * 128 + c0];
    float2 wb = *(const float2*)&W1[(size_t)(128 + k) * 128 + c0];
    h0 = fmaf(a, wt.x, h0); h1 = fmaf(a, wt.y, h1);
    h0 = fmaf(b, wb.x, h0); h1 = fmaf(b, wb.y, h1);
  }
  float s = fmaxf(h0, 0.f) * W2[c0] + fmaxf(h1, 0.f) * W2[c0 + 1];
#pragma unroll
  for (int off = 1; off < 64; off <<= 1) s += __shfl_xor(s, off);
  if (lane == 0) out[edge] = 1.f / (1.f + __expf(-(s + b2[0])));
}

extern "C" void kernel_launch(void* const* d_in, const int* in_sizes, int n_in,
                              void* d_out, int out_size, void* d_ws, size_t ws_size,
                              hipStream_t stream) {
  const float* z  = (const float*)d_in[0];
  const int*   e  = (const int*)d_in[1];
  const float* W1 = (const float*)d_in[2];
  const float* b1 = (const float*)d_in[3];
  const float* W2 = (const float*)d_in[4];
  const float* b2 = (const float*)d_in[5];
  float* out = (float*)d_out;
  const int n_nodes = in_sizes[0] / DD;  // 50000
  const int E = in_sizes[1] / 2;         // 600000

  const size_t g_bytes = (size_t)n_nodes * DD * sizeof(unsigned short);
  const size_t wt_bytes = 256 * 128 * sizeof(unsigned short);  // 64 KB
  const int cap = E / NBK * 2 + 2048;
  const size_t cnt_bytes = 2048;  // 65 u32, padded
  const size_t rec_bytes = (size_t)NBK * cap * sizeof(uint2);
  const size_t ov_bytes = (size_t)OVCAP * sizeof(uint2);
  const size_t need_bucketed =
      2 * g_bytes + wt_bytes + cnt_bytes + rec_bytes + ov_bytes;

  if (ws_size >= need_bucketed && n_nodes <= 65535 && n_nodes > 0) {
    unsigned short* gi = (unsigned short*)d_ws;
    unsigned short* gj = (unsigned short*)((char*)d_ws + g_bytes);
    unsigned short* Wt = (unsigned short*)((char*)d_ws + 2 * g_bytes);
    unsigned int* counters =
        (unsigned int*)((char*)d_ws + 2 * g_bytes + wt_bytes);
    uint2* recs = (uint2*)((char*)d_ws + 2 * g_bytes + wt_bytes + cnt_bytes);
    uint2* ovrecs = (uint2*)((char*)recs + rec_bytes);
    const int ci = (n_nodes + NBI - 1) / NBI;
    const int cj = (n_nodes + NBJ - 1) / NBJ;
    wt_build<<<32, 256, 0, stream>>>(W1, Wt, counters);
    edge_bucket<<<256, 256, 0, stream>>>(e, E, ci, cj, cap, counters, recs, ovrecs);
    node_mfma<<<(n_nodes + 63) / 64, 256, 0, stream>>>(z, Wt, b1, gi, gj, n_nodes);
    edge_mlp_b<<<2048, 256, 0, stream>>>(gi, gj, W2, b2, out, counters, recs,
                                         ovrecs, cap);
  } else if (ws_size >= 2 * g_bytes + wt_bytes) {
    unsigned short* gi = (unsigned short*)d_ws;
    unsigned short* gj = (unsigned short*)((char*)d_ws + g_bytes);
    unsigned short* Wt = (unsigned short*)((char*)d_ws + 2 * g_bytes);
    wt_build<<<32, 256, 0, stream>>>(W1, Wt, nullptr);
    node_mfma<<<(n_nodes + 63) / 64, 256, 0, stream>>>(z, Wt, b1, gi, gj, n_nodes);
    edge_mlp<<<2048, 256, 0, stream>>>(e, gi, gj, W2, b2, out, E);
  } else {
    edge_direct<<<(E + 3) / 4, 256, 0, stream>>>(e, z, W1, b1, W2, b2, out, E);
  }
}